// Round 10
// baseline (591.772 us; speedup 1.0000x reference)
//
#include <hip/hip_runtime.h>
#include <hip/hip_bf16.h>

// Shapes (fixed): B=128, F=8, K=256, D=256, H=256, HFF=512, L=2, M_PREV=2
#define B_   128
#define F_   8
#define K_   256
#define D_   256
#define H_   256
#define HFF_ 512
#define RT   64   // candidates per block

typedef _Float16 half8  __attribute__((ext_vector_type(8)));  // f16x8 MFMA frag
typedef _Float16 half4v __attribute__((ext_vector_type(4)));
typedef float floatx4   __attribute__((ext_vector_type(4)));  // MFMA acc

#define MFMAH(a,b,c) __builtin_amdgcn_mfma_f32_16x16x32_f16(a,b,c,0,0,0)

// LDS strides (halves): 260 -> 130 dwords == 2 mod 32 (conflict-free b128);
// 132 -> 66 dwords == 2 mod 32. Total LDS 53248 B -> 3 blocks/CU.
#define HA_S  260
#define HMA_S 132

// ---------------------------------------------------------------------------
// Fused prep — one launch for (h0->u), v, and the fp16 weight shuffle.
__global__ void k_prep(const float* __restrict__ cb, const float* __restrict__ Win,
                       const float* __restrict__ bin, const float* __restrict__ Wcat,
                       const float* __restrict__ bcat, const float* __restrict__ xhat,
                       const float* __restrict__ W1, const float* __restrict__ W2,
                       const float* __restrict__ Wout,
                       float* __restrict__ u, float* __restrict__ v,
                       _Float16* __restrict__ w1f, _Float16* __restrict__ w2f,
                       _Float16* __restrict__ wof) {
  const int blk = blockIdx.x, t = threadIdx.x;
  if (blk < K_) {
    __shared__ float row[D_];
    __shared__ float h0row[H_];
    row[t] = cb[blk * D_ + t];
    __syncthreads();
    float acc = bin[t];
    #pragma unroll 4
    for (int i = 0; i < D_; ++i) acc = fmaf(row[i], Win[i * H_ + t], acc);
    h0row[t] = acc;
    __syncthreads();
    float acc2 = 0.f;
    #pragma unroll 4
    for (int i = 0; i < H_; ++i) acc2 = fmaf(h0row[i], Wcat[i * H_ + t], acc2);
    u[blk * H_ + t] = acc2;
  } else if (blk < K_ + B_ * F_) {
    __shared__ float row2[D_];
    const int bf = blk - K_;
    row2[t] = xhat[bf * D_ + t];
    __syncthreads();
    float acc = bcat[t];
    #pragma unroll 4
    for (int i = 0; i < D_; ++i) acc = fmaf(row2[i], Wcat[(H_ + i) * H_ + t], acc);
    v[bf * H_ + t] = acc;
  } else {
    const int e = (blk - (K_ + B_ * F_)) * 256 + t;
    const float* src; _Float16* dst; int N, NT, le;
    if (e < 262144) {
      const int layer = e >> 17; le = e & 131071;
      src = W1 + layer * (H_ * HFF_); dst = w1f + layer * (H_ * HFF_);
      N = HFF_; NT = 32;
    } else if (e < 524288) {
      const int e2 = e - 262144;
      const int layer = e2 >> 17; le = e2 & 131071;
      src = W2 + layer * (HFF_ * H_); dst = w2f + layer * (HFF_ * H_);
      N = H_; NT = 16;
    } else {
      le = e - 524288; src = Wout; dst = wof; N = D_; NT = 16;
    }
    const int jj = le & 7, lane = (le >> 3) & 63, r = le >> 9;
    const int ntile = r % NT, kstep = r / NT;
    const int row = kstep * 32 + (lane >> 4) * 8 + jj;
    const int colc = ntile * 16 + (lane & 15);
    dst[le] = (_Float16)src[row * N + colc];
  }
}

// ---------------------------------------------------------------------------
// MFMA main kernel: C' = W^T @ h^T, fp16 single-term, 64 candidates/block.
__global__ __launch_bounds__(256, 3) void k_main(
    const float* __restrict__ u, const float* __restrict__ v,
    const _Float16* __restrict__ w1f, const float* __restrict__ b1,
    const _Float16* __restrict__ w2f, const float* __restrict__ b2,
    const _Float16* __restrict__ woutf, const float* __restrict__ bout,
    const float* __restrict__ cb, const float* __restrict__ xhat,
    const float* __restrict__ x, float* __restrict__ dists) {
  __shared__ _Float16 hA[64][HA_S];    // 33280 B
  __shared__ _Float16 hmA[64][HMA_S];  // 16896 B
  __shared__ float x_s[D_], xh_s[D_];  // 2048 B
  __shared__ float dist_s[4][64];      // 1024 B

  const int t = threadIdx.x;
  const int blk = blockIdx.x;
  const int bf = blk >> 2, k0 = (blk & 3) << 6;
  const int b = bf >> 3, f = bf & 7;
  const int wave = t >> 6, lane = t & 63;
  const int col = lane & 15, quad = lane >> 4;
  const int lane8 = lane * 8;

  x_s[t]  = x[b * D_ + t];
  xh_s[t] = xhat[bf * D_ + t];

  // stage h = u + v -> fp16, packed 16B writes
  {
    const int r = t >> 2, c0 = (t & 3) * 64;
    const float* up = u + (k0 + r) * H_ + c0;
    const float* vp = v + bf * H_ + c0;
    #pragma unroll
    for (int j = 0; j < 64; j += 8) {
      float4 uA = *(const float4*)(up + j);
      float4 vA = *(const float4*)(vp + j);
      float4 uB = *(const float4*)(up + j + 4);
      float4 vB = *(const float4*)(vp + j + 4);
      half8 hv8;
      hv8[0] = (_Float16)(uA.x + vA.x); hv8[1] = (_Float16)(uA.y + vA.y);
      hv8[2] = (_Float16)(uA.z + vA.z); hv8[3] = (_Float16)(uA.w + vA.w);
      hv8[4] = (_Float16)(uB.x + vB.x); hv8[5] = (_Float16)(uB.y + vB.y);
      hv8[6] = (_Float16)(uB.z + vB.z); hv8[7] = (_Float16)(uB.w + vB.w);
      *(half8*)&hA[r][c0 + j] = hv8;
    }
  }
  __syncthreads();

  const floatx4 zero4 = {0.f, 0.f, 0.f, 0.f};

  #pragma unroll 1
  for (int l = 0; l < 2; ++l) {
    const _Float16* w1_l = w1f + l * (H_ * HFF_);
    const _Float16* w2_l = w2f + l * (HFF_ * H_);
    const float* b1l = b1 + l * HFF_;
    const float* b2l = b2 + l * H_;

    floatx4 acc2[4][4];   // [out-feature tile][candidate-row tile]
    #pragma unroll
    for (int mt = 0; mt < 4; ++mt)
      #pragma unroll
      for (int nt = 0; nt < 4; ++nt) acc2[mt][nt] = zero4;

    #pragma unroll 1
    for (int ch = 0; ch < 4; ++ch) {
      // ---- GEMM1': hm' = relu(W1[:,chunk]^T @ h^T + b1) ----
      floatx4 acc1[2][4];
      #pragma unroll
      for (int mt = 0; mt < 2; ++mt)
        #pragma unroll
        for (int nt = 0; nt < 4; ++nt) acc1[mt][nt] = zero4;

      const _Float16* w1_b = w1_l + (ch * 8 + wave * 2) * 512 + lane8;

      #pragma unroll 4
      for (int ks = 0; ks < 8; ++ks) {
        half8 b0 = *(const half8*)&hA[col][ks * 32 + quad * 8];
        half8 b1v = *(const half8*)&hA[16 + col][ks * 32 + quad * 8];
        half8 b2v = *(const half8*)&hA[32 + col][ks * 32 + quad * 8];
        half8 b3v = *(const half8*)&hA[48 + col][ks * 32 + quad * 8];
        const int ko = ks * 32 * 512;
        #pragma unroll
        for (int mt = 0; mt < 2; ++mt) {
          half8 aw = *(const half8*)(w1_b + ko + mt * 512);
          acc1[mt][0] = MFMAH(aw, b0, acc1[mt][0]);
          acc1[mt][1] = MFMAH(aw, b1v, acc1[mt][1]);
          acc1[mt][2] = MFMAH(aw, b2v, acc1[mt][2]);
          acc1[mt][3] = MFMAH(aw, b3v, acc1[mt][3]);
        }
      }
      // bias + relu -> fp16, packed 8B stores (4 consecutive features/lane)
      #pragma unroll
      for (int mt = 0; mt < 2; ++mt) {
        const int floc = (wave * 2 + mt) * 16 + quad * 4;
        float4 bb = *(const float4*)&b1l[ch * 128 + floc];
        #pragma unroll
        for (int nt = 0; nt < 4; ++nt) {
          const int row = nt * 16 + col;
          half4v nh;
          #pragma unroll
          for (int p = 0; p < 4; ++p)
            nh[p] = (_Float16)fmaxf(acc1[mt][nt][p] + ((const float*)&bb)[p], 0.f);
          *(half4v*)&hmA[row][floc] = nh;
        }
      }
      __syncthreads();

      // ---- GEMM2': acc2 += W2[chunk,:]^T @ hm'^T ----
      const _Float16* w2_b = w2_l + (ch * 64 + wave * 4) * 512 + lane8;
      #pragma unroll 2
      for (int ks = 0; ks < 4; ++ks) {
        half8 b0 = *(const half8*)&hmA[col][ks * 32 + quad * 8];
        half8 b1v = *(const half8*)&hmA[16 + col][ks * 32 + quad * 8];
        half8 b2v = *(const half8*)&hmA[32 + col][ks * 32 + quad * 8];
        half8 b3v = *(const half8*)&hmA[48 + col][ks * 32 + quad * 8];
        const int ko = ks * 16 * 512;
        #pragma unroll
        for (int mt = 0; mt < 4; ++mt) {
          half8 aw = *(const half8*)(w2_b + ko + mt * 512);
          acc2[mt][0] = MFMAH(aw, b0, acc2[mt][0]);
          acc2[mt][1] = MFMAH(aw, b1v, acc2[mt][1]);
          acc2[mt][2] = MFMAH(aw, b2v, acc2[mt][2]);
          acc2[mt][3] = MFMAH(aw, b3v, acc2[mt][3]);
        }
      }
      __syncthreads();
    }

    // ---- residual: h += acc2 + b2, packed 8B read/modify/write ----
    #pragma unroll
    for (int mt = 0; mt < 4; ++mt) {
      const int feat0 = (wave * 4 + mt) * 16 + quad * 4;
      float4 bb = *(const float4*)&b2l[feat0];
      #pragma unroll
      for (int nt = 0; nt < 4; ++nt) {
        const int row = nt * 16 + col;
        half4v oh = *(half4v*)&hA[row][feat0];
        half4v nh;
        #pragma unroll
        for (int p = 0; p < 4; ++p)
          nh[p] = (_Float16)((float)oh[p] + acc2[mt][nt][p] + ((const float*)&bb)[p]);
        *(half4v*)&hA[row][feat0] = nh;
      }
    }
    __syncthreads();
  }

  // ---- GEMM3': cw' = Wout^T @ h^T (+bout+cb+xhat), then distance ----
  floatx4 acc3[4][4];
  #pragma unroll
  for (int mt = 0; mt < 4; ++mt)
    #pragma unroll
    for (int nt = 0; nt < 4; ++nt) acc3[mt][nt] = zero4;

  const _Float16* wo_b = woutf + (wave * 4) * 512 + lane8;
  #pragma unroll 2
  for (int ks = 0; ks < 8; ++ks) {
    half8 b0 = *(const half8*)&hA[col][ks * 32 + quad * 8];
    half8 b1v = *(const half8*)&hA[16 + col][ks * 32 + quad * 8];
    half8 b2v = *(const half8*)&hA[32 + col][ks * 32 + quad * 8];
    half8 b3v = *(const half8*)&hA[48 + col][ks * 32 + quad * 8];
    const int ko = ks * 16 * 512;
    #pragma unroll
    for (int mt = 0; mt < 4; ++mt) {
      half8 aw = *(const half8*)(wo_b + ko + mt * 512);
      acc3[mt][0] = MFMAH(aw, b0, acc3[mt][0]);
      acc3[mt][1] = MFMAH(aw, b1v, acc3[mt][1]);
      acc3[mt][2] = MFMAH(aw, b2v, acc3[mt][2]);
      acc3[mt][3] = MFMAH(aw, b3v, acc3[mt][3]);
    }
  }

  float s[4] = {0.f, 0.f, 0.f, 0.f};
  #pragma unroll
  for (int mt = 0; mt < 4; ++mt) {
    const int d0 = (wave * 4 + mt) * 16 + quad * 4;
    float4 bo = *(const float4*)&bout[d0];
    float4 xv = *(const float4*)&x_s[d0];
    float4 xh4 = *(const float4*)&xh_s[d0];
    #pragma unroll
    for (int nt = 0; nt < 4; ++nt) {
      float4 cbv = *(const float4*)&cb[(k0 + nt * 16 + col) * D_ + d0];
      #pragma unroll
      for (int p = 0; p < 4; ++p) {
        float base = ((const float*)&bo)[p] + ((const float*)&xh4)[p];
        float xx = ((const float*)&xv)[p];
        float cw = acc3[mt][nt][p] + base + ((const float*)&cbv)[p];
        s[nt] += cw * (cw - 2.f * xx);   // -||x||^2 const: argmin-invariant
      }
    }
  }
  #pragma unroll
  for (int nt = 0; nt < 4; ++nt) {
    s[nt] += __shfl_xor(s[nt], 16, 64);
    s[nt] += __shfl_xor(s[nt], 32, 64);
  }
  if (quad == 0) {
    #pragma unroll
    for (int nt = 0; nt < 4; ++nt)
      dist_s[wave][nt * 16 + col] = s[nt];
  }
  __syncthreads();
  if (t < 64) {
    float d = dist_s[0][t] + dist_s[1][t] + dist_s[2][t] + dist_s[3][t];
    dists[b * (F_ * K_) + f * K_ + k0 + t] = d;
  }
}

// ---------------------------------------------------------------------------
// R10: fused selection — top8 + shared-weight exact fp32 rescore + argmin +
// output write, one block per b. Weight bytes 8x down vs per-candidate
// rescore (each W element loaded once per block, used for all 8 candidates).
// Rescore math is op-for-op identical (fmaf, same order) to the R2-passing
// per-candidate version.
__global__ __launch_bounds__(256) void k_sel(
    const float* __restrict__ u, const float* __restrict__ v,
    const float* __restrict__ W1, const float* __restrict__ b1,
    const float* __restrict__ W2, const float* __restrict__ b2,
    const float* __restrict__ Wout, const float* __restrict__ bout,
    const float* __restrict__ cb, const float* __restrict__ xhat,
    const float* __restrict__ x, const int* __restrict__ codes,
    const float* __restrict__ dists, float* __restrict__ out) {
  __shared__ float ds[F_ * K_];      // 8 KB
  __shared__ float hs[H_][8];        // 8 KB  [feature][candidate]
  __shared__ float hm[HFF_][8];      // 16 KB
  __shared__ float bv[256];
  __shared__ int bi_s[256];
  __shared__ int topc[8];
  __shared__ float part[4][8];
  __shared__ int win_sh;

  const int b = blockIdx.x, t = threadIdx.x;

  // ---- phase 1: top-8 by approx dist (first-occurrence semantics) ----
  for (int j = t; j < F_ * K_; j += 256) ds[j] = dists[b * (F_ * K_) + j];
  __syncthreads();
  for (int pass = 0; pass < 8; ++pass) {
    float best = 3.4e38f; int bi = 0;
    for (int j = t; j < F_ * K_; j += 256) {
      const float dv = ds[j];
      if (dv < best) { best = dv; bi = j; }
    }
    bv[t] = best; bi_s[t] = bi;
    __syncthreads();
    for (int s = 128; s > 0; s >>= 1) {
      if (t < s) {
        const float ov = bv[t + s]; const int oi = bi_s[t + s];
        if (ov < bv[t] || (ov == bv[t] && oi < bi_s[t])) { bv[t] = ov; bi_s[t] = oi; }
      }
      __syncthreads();
    }
    if (t == 0) { topc[pass] = bi_s[0]; ds[bi_s[0]] = 3.4e38f; }
    __syncthreads();
  }

  int kc[8], bfc[8];
  #pragma unroll
  for (int c = 0; c < 8; ++c) {
    const int idx = topc[c];
    kc[c] = idx & 255;
    bfc[c] = b * F_ + (idx >> 8);
  }

  // ---- phase 2: exact fp32 rescore, 8 candidates share each W load ----
  #pragma unroll
  for (int c = 0; c < 8; ++c)
    hs[t][c] = u[kc[c] * H_ + t] + v[bfc[c] * H_ + t];
  __syncthreads();

  for (int l = 0; l < 2; ++l) {
    const float* W1l = W1 + l * (H_ * HFF_);
    const float* W2l = W2 + l * (HFF_ * H_);
    float a0[8], a1[8];
    {
      const float bb0 = b1[l * HFF_ + t], bb1 = b1[l * HFF_ + 256 + t];
      #pragma unroll
      for (int c = 0; c < 8; ++c) { a0[c] = bb0; a1[c] = bb1; }
    }
    #pragma unroll 4
    for (int i = 0; i < H_; ++i) {
      const float w0 = W1l[i * HFF_ + t];
      const float w1 = W1l[i * HFF_ + 256 + t];
      float hv[8];
      *(float4*)&hv[0] = *(const float4*)&hs[i][0];
      *(float4*)&hv[4] = *(const float4*)&hs[i][4];
      #pragma unroll
      for (int c = 0; c < 8; ++c) {
        a0[c] = fmaf(hv[c], w0, a0[c]);
        a1[c] = fmaf(hv[c], w1, a1[c]);
      }
    }
    #pragma unroll
    for (int c = 0; c < 8; ++c) {
      hm[t][c] = fmaxf(a0[c], 0.f);
      hm[t + 256][c] = fmaxf(a1[c], 0.f);
    }
    __syncthreads();

    float hn[8];
    {
      const float bb = b2[l * H_ + t];
      #pragma unroll
      for (int c = 0; c < 8; ++c) hn[c] = hs[t][c] + bb;
    }
    #pragma unroll 4
    for (int jj = 0; jj < HFF_; ++jj) {
      const float w = W2l[jj * H_ + t];
      float hv[8];
      *(float4*)&hv[0] = *(const float4*)&hm[jj][0];
      *(float4*)&hv[4] = *(const float4*)&hm[jj][4];
      #pragma unroll
      for (int c = 0; c < 8; ++c) hn[c] = fmaf(hv[c], w, hn[c]);
    }
    // own-row write; all cross-row reads (loop1/loop2) completed above
    #pragma unroll
    for (int c = 0; c < 8; ++c) hs[t][c] = hn[c];
    __syncthreads();
  }

  float cw[8];
  #pragma unroll
  for (int c = 0; c < 8; ++c)
    cw[c] = bout[t] + cb[kc[c] * D_ + t] + xhat[bfc[c] * D_ + t];
  #pragma unroll 4
  for (int i = 0; i < H_; ++i) {
    const float w = Wout[i * D_ + t];
    float hv[8];
    *(float4*)&hv[0] = *(const float4*)&hs[i][0];
    *(float4*)&hv[4] = *(const float4*)&hs[i][4];
    #pragma unroll
    for (int c = 0; c < 8; ++c) cw[c] = fmaf(hv[c], w, cw[c]);
  }

  // ---- phase 3: distances, argmin, output ----
  const float xx = x[b * D_ + t];
  float rd[8];
  #pragma unroll
  for (int c = 0; c < 8; ++c) rd[c] = cw[c] * (cw[c] - 2.f * xx);
  #pragma unroll
  for (int m = 1; m < 64; m <<= 1)
    #pragma unroll
    for (int c = 0; c < 8; ++c) rd[c] += __shfl_xor(rd[c], m, 64);
  const int wave = t >> 6, lane = t & 63;
  if (lane == 0) {
    #pragma unroll
    for (int c = 0; c < 8; ++c) part[wave][c] = rd[c];
  }
  __syncthreads();
  if (t == 0) {
    float bd = 3.4e38f; int bwin = 0; int bidx = 1 << 30;
    for (int c = 0; c < 8; ++c) {
      const float d = part[0][c] + part[1][c] + part[2][c] + part[3][c];
      const int ix = topc[c];
      if (d < bd || (d == bd && ix < bidx)) { bd = d; bwin = c; bidx = ix; }
    }
    win_sh = bwin;
  }
  __syncthreads();
  const int win = win_sh;
  float cwsel = cw[0];
  #pragma unroll
  for (int c = 1; c < 8; ++c) cwsel = (win == c) ? cw[c] : cwsel;
  out[b * D_ + t] = cwsel;
  if (t < 2)
    out[B_ * D_ + t * B_ + b] = (float)codes[t * B_ + b];
  else if (t == 2)
    out[B_ * D_ + 2 * B_ + b] = (float)topc[win];
}

// ---------------------------------------------------------------------------
extern "C" void kernel_launch(void* const* d_in, const int* in_sizes, int n_in,
                              void* d_out, int out_size, void* d_ws, size_t ws_size,
                              hipStream_t stream) {
  const float* x    = (const float*)d_in[0];
  const float* xhat = (const float*)d_in[1];
  const int*   codes= (const int*)d_in[2];
  const float* cb   = (const float*)d_in[3];
  const float* Win  = (const float*)d_in[4];
  const float* bin  = (const float*)d_in[5];
  const float* Wcat = (const float*)d_in[6];
  const float* bcat = (const float*)d_in[7];
  const float* W1   = (const float*)d_in[8];
  const float* b1   = (const float*)d_in[9];
  const float* W2   = (const float*)d_in[10];
  const float* b2   = (const float*)d_in[11];
  const float* Wout = (const float*)d_in[12];
  const float* bout = (const float*)d_in[13];
  float* out = (float*)d_out;

  float* u     = (float*)d_ws;                  // 65536 f
  float* v     = u + K_ * H_;                   // 262144 f
  float* dists = v + B_ * F_ * H_;              // 262144 f
  float* pad   = dists + B_ * F_ * K_;          // 256 f pad (16B align)
  _Float16* w1f  = (_Float16*)(pad + 256);      // 2*H*HFF halves
  _Float16* w2f  = w1f + 2 * H_ * HFF_;
  _Float16* wof  = w2f + 2 * HFF_ * H_;

  k_prep<<<K_ + B_ * F_ + 2304, 256, 0, stream>>>(cb, Win, bin, Wcat, bcat, xhat,
                                                  W1, W2, Wout, u, v, w1f, w2f, wof);

  k_main<<<B_ * F_ * (K_ / RT), 256, 0, stream>>>(u, v, w1f, b1, w2f, b2,
                                                  wof, bout, cb, xhat, x, dists);

  k_sel<<<B_, 256, 0, stream>>>(u, v, W1, b1, W2, b2, Wout, bout, cb, xhat,
                                x, codes, dists, out);
}

// Round 11
// 590.573 us; speedup vs baseline: 1.0020x; 1.0020x over previous
//
#include <hip/hip_runtime.h>
#include <hip/hip_bf16.h>

// Shapes (fixed): B=128, F=8, K=256, D=256, H=256, HFF=512, L=2, M_PREV=2
#define B_   128
#define F_   8
#define K_   256
#define D_   256
#define H_   256
#define HFF_ 512
#define RT   64   // candidates per block

typedef _Float16 half8  __attribute__((ext_vector_type(8)));  // f16x8 MFMA frag
typedef _Float16 half4v __attribute__((ext_vector_type(4)));
typedef float floatx4   __attribute__((ext_vector_type(4)));  // MFMA acc

#define MFMAH(a,b,c) __builtin_amdgcn_mfma_f32_16x16x32_f16(a,b,c,0,0,0)

// LDS strides (halves): 260 -> 130 dwords == 2 mod 32 (conflict-free b128);
// 132 -> 66 dwords == 2 mod 32. Total LDS 53248 B -> 3 blocks/CU.
#define HA_S  260
#define HMA_S 132

// ---------------------------------------------------------------------------
// Fused prep — one launch for (h0->u), v, and the fp16 weight shuffle.
__global__ void k_prep(const float* __restrict__ cb, const float* __restrict__ Win,
                       const float* __restrict__ bin, const float* __restrict__ Wcat,
                       const float* __restrict__ bcat, const float* __restrict__ xhat,
                       const float* __restrict__ W1, const float* __restrict__ W2,
                       const float* __restrict__ Wout,
                       float* __restrict__ u, float* __restrict__ v,
                       _Float16* __restrict__ w1f, _Float16* __restrict__ w2f,
                       _Float16* __restrict__ wof) {
  const int blk = blockIdx.x, t = threadIdx.x;
  if (blk < K_) {
    __shared__ float row[D_];
    __shared__ float h0row[H_];
    row[t] = cb[blk * D_ + t];
    __syncthreads();
    float acc = bin[t];
    #pragma unroll 4
    for (int i = 0; i < D_; ++i) acc = fmaf(row[i], Win[i * H_ + t], acc);
    h0row[t] = acc;
    __syncthreads();
    float acc2 = 0.f;
    #pragma unroll 4
    for (int i = 0; i < H_; ++i) acc2 = fmaf(h0row[i], Wcat[i * H_ + t], acc2);
    u[blk * H_ + t] = acc2;
  } else if (blk < K_ + B_ * F_) {
    __shared__ float row2[D_];
    const int bf = blk - K_;
    row2[t] = xhat[bf * D_ + t];
    __syncthreads();
    float acc = bcat[t];
    #pragma unroll 4
    for (int i = 0; i < D_; ++i) acc = fmaf(row2[i], Wcat[(H_ + i) * H_ + t], acc);
    v[bf * H_ + t] = acc;
  } else {
    const int e = (blk - (K_ + B_ * F_)) * 256 + t;
    const float* src; _Float16* dst; int N, NT, le;
    if (e < 262144) {
      const int layer = e >> 17; le = e & 131071;
      src = W1 + layer * (H_ * HFF_); dst = w1f + layer * (H_ * HFF_);
      N = HFF_; NT = 32;
    } else if (e < 524288) {
      const int e2 = e - 262144;
      const int layer = e2 >> 17; le = e2 & 131071;
      src = W2 + layer * (HFF_ * H_); dst = w2f + layer * (HFF_ * H_);
      N = H_; NT = 16;
    } else {
      le = e - 524288; src = Wout; dst = wof; N = D_; NT = 16;
    }
    const int jj = le & 7, lane = (le >> 3) & 63, r = le >> 9;
    const int ntile = r % NT, kstep = r / NT;
    const int row = kstep * 32 + (lane >> 4) * 8 + jj;
    const int colc = ntile * 16 + (lane & 15);
    dst[le] = (_Float16)src[row * N + colc];
  }
}

// ---------------------------------------------------------------------------
// MFMA main kernel: C' = W^T @ h^T, fp16 single-term, 64 candidates/block.
__global__ __launch_bounds__(256, 3) void k_main(
    const float* __restrict__ u, const float* __restrict__ v,
    const _Float16* __restrict__ w1f, const float* __restrict__ b1,
    const _Float16* __restrict__ w2f, const float* __restrict__ b2,
    const _Float16* __restrict__ woutf, const float* __restrict__ bout,
    const float* __restrict__ cb, const float* __restrict__ xhat,
    const float* __restrict__ x, float* __restrict__ dists) {
  __shared__ _Float16 hA[64][HA_S];    // 33280 B
  __shared__ _Float16 hmA[64][HMA_S];  // 16896 B
  __shared__ float x_s[D_], xh_s[D_];  // 2048 B
  __shared__ float dist_s[4][64];      // 1024 B

  const int t = threadIdx.x;
  const int blk = blockIdx.x;
  const int bf = blk >> 2, k0 = (blk & 3) << 6;
  const int b = bf >> 3, f = bf & 7;
  const int wave = t >> 6, lane = t & 63;
  const int col = lane & 15, quad = lane >> 4;
  const int lane8 = lane * 8;

  x_s[t]  = x[b * D_ + t];
  xh_s[t] = xhat[bf * D_ + t];

  // stage h = u + v -> fp16, packed 16B writes
  {
    const int r = t >> 2, c0 = (t & 3) * 64;
    const float* up = u + (k0 + r) * H_ + c0;
    const float* vp = v + bf * H_ + c0;
    #pragma unroll
    for (int j = 0; j < 64; j += 8) {
      float4 uA = *(const float4*)(up + j);
      float4 vA = *(const float4*)(vp + j);
      float4 uB = *(const float4*)(up + j + 4);
      float4 vB = *(const float4*)(vp + j + 4);
      half8 hv8;
      hv8[0] = (_Float16)(uA.x + vA.x); hv8[1] = (_Float16)(uA.y + vA.y);
      hv8[2] = (_Float16)(uA.z + vA.z); hv8[3] = (_Float16)(uA.w + vA.w);
      hv8[4] = (_Float16)(uB.x + vB.x); hv8[5] = (_Float16)(uB.y + vB.y);
      hv8[6] = (_Float16)(uB.z + vB.z); hv8[7] = (_Float16)(uB.w + vB.w);
      *(half8*)&hA[r][c0 + j] = hv8;
    }
  }
  __syncthreads();

  const floatx4 zero4 = {0.f, 0.f, 0.f, 0.f};

  #pragma unroll 1
  for (int l = 0; l < 2; ++l) {
    const _Float16* w1_l = w1f + l * (H_ * HFF_);
    const _Float16* w2_l = w2f + l * (HFF_ * H_);
    const float* b1l = b1 + l * HFF_;
    const float* b2l = b2 + l * H_;

    floatx4 acc2[4][4];   // [out-feature tile][candidate-row tile]
    #pragma unroll
    for (int mt = 0; mt < 4; ++mt)
      #pragma unroll
      for (int nt = 0; nt < 4; ++nt) acc2[mt][nt] = zero4;

    #pragma unroll 1
    for (int ch = 0; ch < 4; ++ch) {
      // ---- GEMM1': hm' = relu(W1[:,chunk]^T @ h^T + b1) ----
      floatx4 acc1[2][4];
      #pragma unroll
      for (int mt = 0; mt < 2; ++mt)
        #pragma unroll
        for (int nt = 0; nt < 4; ++nt) acc1[mt][nt] = zero4;

      const _Float16* w1_b = w1_l + (ch * 8 + wave * 2) * 512 + lane8;

      #pragma unroll 4
      for (int ks = 0; ks < 8; ++ks) {
        half8 b0 = *(const half8*)&hA[col][ks * 32 + quad * 8];
        half8 b1v = *(const half8*)&hA[16 + col][ks * 32 + quad * 8];
        half8 b2v = *(const half8*)&hA[32 + col][ks * 32 + quad * 8];
        half8 b3v = *(const half8*)&hA[48 + col][ks * 32 + quad * 8];
        const int ko = ks * 32 * 512;
        #pragma unroll
        for (int mt = 0; mt < 2; ++mt) {
          half8 aw = *(const half8*)(w1_b + ko + mt * 512);
          acc1[mt][0] = MFMAH(aw, b0, acc1[mt][0]);
          acc1[mt][1] = MFMAH(aw, b1v, acc1[mt][1]);
          acc1[mt][2] = MFMAH(aw, b2v, acc1[mt][2]);
          acc1[mt][3] = MFMAH(aw, b3v, acc1[mt][3]);
        }
      }
      // bias + relu -> fp16, packed 8B stores (4 consecutive features/lane)
      #pragma unroll
      for (int mt = 0; mt < 2; ++mt) {
        const int floc = (wave * 2 + mt) * 16 + quad * 4;
        float4 bb = *(const float4*)&b1l[ch * 128 + floc];
        #pragma unroll
        for (int nt = 0; nt < 4; ++nt) {
          const int row = nt * 16 + col;
          half4v nh;
          #pragma unroll
          for (int p = 0; p < 4; ++p)
            nh[p] = (_Float16)fmaxf(acc1[mt][nt][p] + ((const float*)&bb)[p], 0.f);
          *(half4v*)&hmA[row][floc] = nh;
        }
      }
      __syncthreads();

      // ---- GEMM2': acc2 += W2[chunk,:]^T @ hm'^T ----
      const _Float16* w2_b = w2_l + (ch * 64 + wave * 4) * 512 + lane8;
      #pragma unroll 2
      for (int ks = 0; ks < 4; ++ks) {
        half8 b0 = *(const half8*)&hmA[col][ks * 32 + quad * 8];
        half8 b1v = *(const half8*)&hmA[16 + col][ks * 32 + quad * 8];
        half8 b2v = *(const half8*)&hmA[32 + col][ks * 32 + quad * 8];
        half8 b3v = *(const half8*)&hmA[48 + col][ks * 32 + quad * 8];
        const int ko = ks * 16 * 512;
        #pragma unroll
        for (int mt = 0; mt < 4; ++mt) {
          half8 aw = *(const half8*)(w2_b + ko + mt * 512);
          acc2[mt][0] = MFMAH(aw, b0, acc2[mt][0]);
          acc2[mt][1] = MFMAH(aw, b1v, acc2[mt][1]);
          acc2[mt][2] = MFMAH(aw, b2v, acc2[mt][2]);
          acc2[mt][3] = MFMAH(aw, b3v, acc2[mt][3]);
        }
      }
      __syncthreads();
    }

    // ---- residual: h += acc2 + b2, packed 8B read/modify/write ----
    #pragma unroll
    for (int mt = 0; mt < 4; ++mt) {
      const int feat0 = (wave * 4 + mt) * 16 + quad * 4;
      float4 bb = *(const float4*)&b2l[feat0];
      #pragma unroll
      for (int nt = 0; nt < 4; ++nt) {
        const int row = nt * 16 + col;
        half4v oh = *(half4v*)&hA[row][feat0];
        half4v nh;
        #pragma unroll
        for (int p = 0; p < 4; ++p)
          nh[p] = (_Float16)((float)oh[p] + acc2[mt][nt][p] + ((const float*)&bb)[p]);
        *(half4v*)&hA[row][feat0] = nh;
      }
    }
    __syncthreads();
  }

  // ---- GEMM3': cw' = Wout^T @ h^T (+bout+cb+xhat), then distance ----
  floatx4 acc3[4][4];
  #pragma unroll
  for (int mt = 0; mt < 4; ++mt)
    #pragma unroll
    for (int nt = 0; nt < 4; ++nt) acc3[mt][nt] = zero4;

  const _Float16* wo_b = woutf + (wave * 4) * 512 + lane8;
  #pragma unroll 2
  for (int ks = 0; ks < 8; ++ks) {
    half8 b0 = *(const half8*)&hA[col][ks * 32 + quad * 8];
    half8 b1v = *(const half8*)&hA[16 + col][ks * 32 + quad * 8];
    half8 b2v = *(const half8*)&hA[32 + col][ks * 32 + quad * 8];
    half8 b3v = *(const half8*)&hA[48 + col][ks * 32 + quad * 8];
    const int ko = ks * 16 * 512;
    #pragma unroll
    for (int mt = 0; mt < 4; ++mt) {
      half8 aw = *(const half8*)(wo_b + ko + mt * 512);
      acc3[mt][0] = MFMAH(aw, b0, acc3[mt][0]);
      acc3[mt][1] = MFMAH(aw, b1v, acc3[mt][1]);
      acc3[mt][2] = MFMAH(aw, b2v, acc3[mt][2]);
      acc3[mt][3] = MFMAH(aw, b3v, acc3[mt][3]);
    }
  }

  float s[4] = {0.f, 0.f, 0.f, 0.f};
  #pragma unroll
  for (int mt = 0; mt < 4; ++mt) {
    const int d0 = (wave * 4 + mt) * 16 + quad * 4;
    float4 bo = *(const float4*)&bout[d0];
    float4 xv = *(const float4*)&x_s[d0];
    float4 xh4 = *(const float4*)&xh_s[d0];
    #pragma unroll
    for (int nt = 0; nt < 4; ++nt) {
      float4 cbv = *(const float4*)&cb[(k0 + nt * 16 + col) * D_ + d0];
      #pragma unroll
      for (int p = 0; p < 4; ++p) {
        float base = ((const float*)&bo)[p] + ((const float*)&xh4)[p];
        float xx = ((const float*)&xv)[p];
        float cw = acc3[mt][nt][p] + base + ((const float*)&cbv)[p];
        s[nt] += cw * (cw - 2.f * xx);   // -||x||^2 const: argmin-invariant
      }
    }
  }
  #pragma unroll
  for (int nt = 0; nt < 4; ++nt) {
    s[nt] += __shfl_xor(s[nt], 16, 64);
    s[nt] += __shfl_xor(s[nt], 32, 64);
  }
  if (quad == 0) {
    #pragma unroll
    for (int nt = 0; nt < 4; ++nt)
      dist_s[wave][nt * 16 + col] = s[nt];
  }
  __syncthreads();
  if (t < 64) {
    float d = dist_s[0][t] + dist_s[1][t] + dist_s[2][t] + dist_s[3][t];
    dists[b * (F_ * K_) + f * K_ + k0 + t] = d;
  }
}

// ---------------------------------------------------------------------------
// Top-8 candidates per b from approx dists (iterative selection).
__global__ void k_top8(const float* __restrict__ dists, int* __restrict__ topi) {
  __shared__ float ds[F_ * K_];
  __shared__ float bv[256];
  __shared__ int bi_s[256];
  const int b = blockIdx.x, t = threadIdx.x;
  for (int j = t; j < F_ * K_; j += 256) ds[j] = dists[b * (F_ * K_) + j];
  __syncthreads();
  for (int pass = 0; pass < 8; ++pass) {
    float best = 3.4e38f; int bi = 0;
    for (int j = t; j < F_ * K_; j += 256) {
      const float dv = ds[j];
      if (dv < best) { best = dv; bi = j; }
    }
    bv[t] = best; bi_s[t] = bi;
    __syncthreads();
    for (int s = 128; s > 0; s >>= 1) {
      if (t < s) {
        const float ov = bv[t + s]; const int oi = bi_s[t + s];
        if (ov < bv[t] || (ov == bv[t] && oi < bi_s[t])) { bv[t] = ov; bi_s[t] = oi; }
      }
      __syncthreads();
    }
    if (t == 0) { topi[b * 8 + pass] = bi_s[0]; ds[bi_s[0]] = 3.4e38f; }
    __syncthreads();
  }
}

// ---------------------------------------------------------------------------
// R11: exact fp32 rescore, TWO candidates per block (512 blocks): shares each
// weight load across both, per-candidate fmaf chains in op-for-op identical
// order to the R2-passing version. Also writes the full cw row per candidate
// so k_final needs no MLP.
__global__ __launch_bounds__(256) void k_rescore(
    const float* __restrict__ u, const float* __restrict__ v,
    const float* __restrict__ W1, const float* __restrict__ b1,
    const float* __restrict__ W2, const float* __restrict__ b2,
    const float* __restrict__ Wout, const float* __restrict__ bout,
    const float* __restrict__ cb, const float* __restrict__ xhat,
    const float* __restrict__ x, const int* __restrict__ topi,
    float* __restrict__ resc, float* __restrict__ cwr) {
  __shared__ float hsA[H_], hsB[H_];
  __shared__ float hmA2[HFF_], hmB2[HFF_];
  __shared__ float redA[256], redB[256];
  const int blk = blockIdx.x, t = threadIdx.x;
  const int b = blk >> 2;
  const int c0 = (blk & 3) * 2;          // candidates c0, c0+1
  const int bcA = b * 8 + c0, bcB = bcA + 1;
  const int idxA = topi[bcA], idxB = topi[bcB];
  const int kA = idxA & 255, kB = idxB & 255;
  const int bfA = b * F_ + (idxA >> 8), bfB = b * F_ + (idxB >> 8);

  hsA[t] = u[kA * H_ + t] + v[bfA * H_ + t];
  hsB[t] = u[kB * H_ + t] + v[bfB * H_ + t];
  __syncthreads();
  for (int l = 0; l < 2; ++l) {
    const float* W1l = W1 + l * (H_ * HFF_);
    const float* W2l = W2 + l * (HFF_ * H_);
    const float bb0 = b1[l * HFF_ + t], bb1 = b1[l * HFF_ + 256 + t];
    float a0A = bb0, a1A = bb1, a0B = bb0, a1B = bb1;
    #pragma unroll 4
    for (int i = 0; i < H_; ++i) {
      const float w0 = W1l[i * HFF_ + t];
      const float w1 = W1l[i * HFF_ + 256 + t];
      const float hA = hsA[i], hB = hsB[i];
      a0A = fmaf(hA, w0, a0A);
      a1A = fmaf(hA, w1, a1A);
      a0B = fmaf(hB, w0, a0B);
      a1B = fmaf(hB, w1, a1B);
    }
    hmA2[t] = fmaxf(a0A, 0.f);  hmA2[t + 256] = fmaxf(a1A, 0.f);
    hmB2[t] = fmaxf(a0B, 0.f);  hmB2[t + 256] = fmaxf(a1B, 0.f);
    __syncthreads();
    const float bb2 = b2[l * H_ + t];
    float hnA = hsA[t] + bb2, hnB = hsB[t] + bb2;
    #pragma unroll 4
    for (int jj = 0; jj < HFF_; ++jj) {
      const float w = W2l[jj * H_ + t];
      hnA = fmaf(hmA2[jj], w, hnA);
      hnB = fmaf(hmB2[jj], w, hnB);
    }
    __syncthreads();
    hsA[t] = hnA; hsB[t] = hnB;
    __syncthreads();
  }
  float cwA = bout[t] + cb[kA * D_ + t] + xhat[bfA * D_ + t];
  float cwB = bout[t] + cb[kB * D_ + t] + xhat[bfB * D_ + t];
  #pragma unroll 4
  for (int i = 0; i < H_; ++i) {
    const float w = Wout[i * D_ + t];
    cwA = fmaf(hsA[i], w, cwA);
    cwB = fmaf(hsB[i], w, cwB);
  }
  cwr[bcA * D_ + t] = cwA;
  cwr[bcB * D_ + t] = cwB;
  const float xx = x[b * D_ + t];
  redA[t] = cwA * (cwA - 2.f * xx);
  redB[t] = cwB * (cwB - 2.f * xx);
  __syncthreads();
  for (int s = 128; s > 0; s >>= 1) {
    if (t < s) { redA[t] += redA[t + s]; redB[t] += redB[t + s]; }
    __syncthreads();
  }
  if (t == 0) { resc[bcA] = redA[0]; resc[bcB] = redB[0]; }
}

// ---------------------------------------------------------------------------
// R11: trivial final — argmin over the 8 rescored candidates, copy cw row.
__global__ void k_final(const int* __restrict__ codes, const int* __restrict__ topi,
                        const float* __restrict__ resc, const float* __restrict__ cwr,
                        float* __restrict__ out) {
  __shared__ int win_sh;
  const int b = blockIdx.x, t = threadIdx.x;
  if (t == 0) {
    float bd = 3.4e38f; int bwin = 0; int bidx = 1 << 30;
    for (int c = 0; c < 8; ++c) {
      const float d = resc[b * 8 + c];
      const int ix = topi[b * 8 + c];
      if (d < bd || (d == bd && ix < bidx)) { bd = d; bwin = c; bidx = ix; }
    }
    win_sh = bwin;
  }
  __syncthreads();
  const int win = win_sh;
  out[b * D_ + t] = cwr[(b * 8 + win) * D_ + t];
  if (t < 2)
    out[B_ * D_ + t * B_ + b] = (float)codes[t * B_ + b];
  else if (t == 2)
    out[B_ * D_ + 2 * B_ + b] = (float)topi[b * 8 + win];
}

// ---------------------------------------------------------------------------
extern "C" void kernel_launch(void* const* d_in, const int* in_sizes, int n_in,
                              void* d_out, int out_size, void* d_ws, size_t ws_size,
                              hipStream_t stream) {
  const float* x    = (const float*)d_in[0];
  const float* xhat = (const float*)d_in[1];
  const int*   codes= (const int*)d_in[2];
  const float* cb   = (const float*)d_in[3];
  const float* Win  = (const float*)d_in[4];
  const float* bin  = (const float*)d_in[5];
  const float* Wcat = (const float*)d_in[6];
  const float* bcat = (const float*)d_in[7];
  const float* W1   = (const float*)d_in[8];
  const float* b1   = (const float*)d_in[9];
  const float* W2   = (const float*)d_in[10];
  const float* b2   = (const float*)d_in[11];
  const float* Wout = (const float*)d_in[12];
  const float* bout = (const float*)d_in[13];
  float* out = (float*)d_out;

  float* u     = (float*)d_ws;                  // 65536 f
  float* v     = u + K_ * H_;                   // 262144 f
  float* dists = v + B_ * F_ * H_;              // 262144 f
  float* resc  = dists + B_ * F_ * K_;          // 1024 f
  int*   topi  = (int*)(resc + 1024);           // 1024 i
  float* cwr   = (float*)(topi + 1024);         // 262144 f (8 cand x 256 per b)
  float* pad   = cwr + B_ * 8 * D_;             // 128 f pad (16B align)
  _Float16* w1f  = (_Float16*)(pad + 128);      // 2*H*HFF halves
  _Float16* w2f  = w1f + 2 * H_ * HFF_;
  _Float16* wof  = w2f + 2 * HFF_ * H_;

  k_prep<<<K_ + B_ * F_ + 2304, 256, 0, stream>>>(cb, Win, bin, Wcat, bcat, xhat,
                                                  W1, W2, Wout, u, v, w1f, w2f, wof);

  k_main<<<B_ * F_ * (K_ / RT), 256, 0, stream>>>(u, v, w1f, b1, w2f, b2,
                                                  wof, bout, cb, xhat, x, dists);

  k_top8<<<B_, 256, 0, stream>>>(dists, topi);
  k_rescore<<<B_ * 4, 256, 0, stream>>>(u, v, W1, b1, W2, b2, Wout, bout, cb, xhat,
                                        x, topi, resc, cwr);
  k_final<<<B_, 256, 0, stream>>>(codes, topi, resc, cwr, out);
}

// Round 12
// 575.715 us; speedup vs baseline: 1.0279x; 1.0258x over previous
//
#include <hip/hip_runtime.h>
#include <hip/hip_bf16.h>

// Shapes (fixed): B=128, F=8, K=256, D=256, H=256, HFF=512, L=2, M_PREV=2
#define B_   128
#define F_   8
#define K_   256
#define D_   256
#define H_   256
#define HFF_ 512
#define RT   64   // candidates per block

typedef _Float16 half8  __attribute__((ext_vector_type(8)));  // f16x8 MFMA frag
typedef _Float16 half4v __attribute__((ext_vector_type(4)));
typedef float floatx4   __attribute__((ext_vector_type(4)));  // MFMA acc

#define MFMAH(a,b,c) __builtin_amdgcn_mfma_f32_16x16x32_f16(a,b,c,0,0,0)

// LDS strides (halves): 260 -> 130 dwords == 2 mod 32 (conflict-free b128);
// 132 -> 66 dwords == 2 mod 32. Total LDS 53248 B -> 3 blocks/CU.
#define HA_S  260
#define HMA_S 132

// ---------------------------------------------------------------------------
// Fused prep — one launch for (h0->u), v, and the fp16 weight shuffle.
__global__ void k_prep(const float* __restrict__ cb, const float* __restrict__ Win,
                       const float* __restrict__ bin, const float* __restrict__ Wcat,
                       const float* __restrict__ bcat, const float* __restrict__ xhat,
                       const float* __restrict__ W1, const float* __restrict__ W2,
                       const float* __restrict__ Wout,
                       float* __restrict__ u, float* __restrict__ v,
                       _Float16* __restrict__ w1f, _Float16* __restrict__ w2f,
                       _Float16* __restrict__ wof) {
  const int blk = blockIdx.x, t = threadIdx.x;
  if (blk < K_) {
    __shared__ float row[D_];
    __shared__ float h0row[H_];
    row[t] = cb[blk * D_ + t];
    __syncthreads();
    float acc = bin[t];
    #pragma unroll 4
    for (int i = 0; i < D_; ++i) acc = fmaf(row[i], Win[i * H_ + t], acc);
    h0row[t] = acc;
    __syncthreads();
    float acc2 = 0.f;
    #pragma unroll 4
    for (int i = 0; i < H_; ++i) acc2 = fmaf(h0row[i], Wcat[i * H_ + t], acc2);
    u[blk * H_ + t] = acc2;
  } else if (blk < K_ + B_ * F_) {
    __shared__ float row2[D_];
    const int bf = blk - K_;
    row2[t] = xhat[bf * D_ + t];
    __syncthreads();
    float acc = bcat[t];
    #pragma unroll 4
    for (int i = 0; i < D_; ++i) acc = fmaf(row2[i], Wcat[(H_ + i) * H_ + t], acc);
    v[bf * H_ + t] = acc;
  } else {
    const int e = (blk - (K_ + B_ * F_)) * 256 + t;
    const float* src; _Float16* dst; int N, NT, le;
    if (e < 262144) {
      const int layer = e >> 17; le = e & 131071;
      src = W1 + layer * (H_ * HFF_); dst = w1f + layer * (H_ * HFF_);
      N = HFF_; NT = 32;
    } else if (e < 524288) {
      const int e2 = e - 262144;
      const int layer = e2 >> 17; le = e2 & 131071;
      src = W2 + layer * (HFF_ * H_); dst = w2f + layer * (HFF_ * H_);
      N = H_; NT = 16;
    } else {
      le = e - 524288; src = Wout; dst = wof; N = D_; NT = 16;
    }
    const int jj = le & 7, lane = (le >> 3) & 63, r = le >> 9;
    const int ntile = r % NT, kstep = r / NT;
    const int row = kstep * 32 + (lane >> 4) * 8 + jj;
    const int colc = ntile * 16 + (lane & 15);
    dst[le] = (_Float16)src[row * N + colc];
  }
}

// ---------------------------------------------------------------------------
// MFMA main kernel: C' = W^T @ h^T, fp16 single-term, 64 candidates/block.
__global__ __launch_bounds__(256, 3) void k_main(
    const float* __restrict__ u, const float* __restrict__ v,
    const _Float16* __restrict__ w1f, const float* __restrict__ b1,
    const _Float16* __restrict__ w2f, const float* __restrict__ b2,
    const _Float16* __restrict__ woutf, const float* __restrict__ bout,
    const float* __restrict__ cb, const float* __restrict__ xhat,
    const float* __restrict__ x, float* __restrict__ dists) {
  __shared__ _Float16 hA[64][HA_S];    // 33280 B
  __shared__ _Float16 hmA[64][HMA_S];  // 16896 B
  __shared__ float x_s[D_], xh_s[D_];  // 2048 B
  __shared__ float dist_s[4][64];      // 1024 B

  const int t = threadIdx.x;
  const int blk = blockIdx.x;
  const int bf = blk >> 2, k0 = (blk & 3) << 6;
  const int b = bf >> 3, f = bf & 7;
  const int wave = t >> 6, lane = t & 63;
  const int col = lane & 15, quad = lane >> 4;
  const int lane8 = lane * 8;

  x_s[t]  = x[b * D_ + t];
  xh_s[t] = xhat[bf * D_ + t];

  // stage h = u + v -> fp16, packed 16B writes
  {
    const int r = t >> 2, c0 = (t & 3) * 64;
    const float* up = u + (k0 + r) * H_ + c0;
    const float* vp = v + bf * H_ + c0;
    #pragma unroll
    for (int j = 0; j < 64; j += 8) {
      float4 uA = *(const float4*)(up + j);
      float4 vA = *(const float4*)(vp + j);
      float4 uB = *(const float4*)(up + j + 4);
      float4 vB = *(const float4*)(vp + j + 4);
      half8 hv8;
      hv8[0] = (_Float16)(uA.x + vA.x); hv8[1] = (_Float16)(uA.y + vA.y);
      hv8[2] = (_Float16)(uA.z + vA.z); hv8[3] = (_Float16)(uA.w + vA.w);
      hv8[4] = (_Float16)(uB.x + vB.x); hv8[5] = (_Float16)(uB.y + vB.y);
      hv8[6] = (_Float16)(uB.z + vB.z); hv8[7] = (_Float16)(uB.w + vB.w);
      *(half8*)&hA[r][c0 + j] = hv8;
    }
  }
  __syncthreads();

  const floatx4 zero4 = {0.f, 0.f, 0.f, 0.f};

  #pragma unroll 1
  for (int l = 0; l < 2; ++l) {
    const _Float16* w1_l = w1f + l * (H_ * HFF_);
    const _Float16* w2_l = w2f + l * (HFF_ * H_);
    const float* b1l = b1 + l * HFF_;
    const float* b2l = b2 + l * H_;

    floatx4 acc2[4][4];   // [out-feature tile][candidate-row tile]
    #pragma unroll
    for (int mt = 0; mt < 4; ++mt)
      #pragma unroll
      for (int nt = 0; nt < 4; ++nt) acc2[mt][nt] = zero4;

    #pragma unroll 1
    for (int ch = 0; ch < 4; ++ch) {
      // ---- GEMM1': hm' = relu(W1[:,chunk]^T @ h^T + b1) ----
      floatx4 acc1[2][4];
      #pragma unroll
      for (int mt = 0; mt < 2; ++mt)
        #pragma unroll
        for (int nt = 0; nt < 4; ++nt) acc1[mt][nt] = zero4;

      const _Float16* w1_b = w1_l + (ch * 8 + wave * 2) * 512 + lane8;

      #pragma unroll 4
      for (int ks = 0; ks < 8; ++ks) {
        half8 b0 = *(const half8*)&hA[col][ks * 32 + quad * 8];
        half8 b1v = *(const half8*)&hA[16 + col][ks * 32 + quad * 8];
        half8 b2v = *(const half8*)&hA[32 + col][ks * 32 + quad * 8];
        half8 b3v = *(const half8*)&hA[48 + col][ks * 32 + quad * 8];
        const int ko = ks * 32 * 512;
        #pragma unroll
        for (int mt = 0; mt < 2; ++mt) {
          half8 aw = *(const half8*)(w1_b + ko + mt * 512);
          acc1[mt][0] = MFMAH(aw, b0, acc1[mt][0]);
          acc1[mt][1] = MFMAH(aw, b1v, acc1[mt][1]);
          acc1[mt][2] = MFMAH(aw, b2v, acc1[mt][2]);
          acc1[mt][3] = MFMAH(aw, b3v, acc1[mt][3]);
        }
      }
      // bias + relu -> fp16, packed 8B stores (4 consecutive features/lane)
      #pragma unroll
      for (int mt = 0; mt < 2; ++mt) {
        const int floc = (wave * 2 + mt) * 16 + quad * 4;
        float4 bb = *(const float4*)&b1l[ch * 128 + floc];
        #pragma unroll
        for (int nt = 0; nt < 4; ++nt) {
          const int row = nt * 16 + col;
          half4v nh;
          #pragma unroll
          for (int p = 0; p < 4; ++p)
            nh[p] = (_Float16)fmaxf(acc1[mt][nt][p] + ((const float*)&bb)[p], 0.f);
          *(half4v*)&hmA[row][floc] = nh;
        }
      }
      __syncthreads();

      // ---- GEMM2': acc2 += W2[chunk,:]^T @ hm'^T ----
      const _Float16* w2_b = w2_l + (ch * 64 + wave * 4) * 512 + lane8;
      #pragma unroll 2
      for (int ks = 0; ks < 4; ++ks) {
        half8 b0 = *(const half8*)&hmA[col][ks * 32 + quad * 8];
        half8 b1v = *(const half8*)&hmA[16 + col][ks * 32 + quad * 8];
        half8 b2v = *(const half8*)&hmA[32 + col][ks * 32 + quad * 8];
        half8 b3v = *(const half8*)&hmA[48 + col][ks * 32 + quad * 8];
        const int ko = ks * 16 * 512;
        #pragma unroll
        for (int mt = 0; mt < 4; ++mt) {
          half8 aw = *(const half8*)(w2_b + ko + mt * 512);
          acc2[mt][0] = MFMAH(aw, b0, acc2[mt][0]);
          acc2[mt][1] = MFMAH(aw, b1v, acc2[mt][1]);
          acc2[mt][2] = MFMAH(aw, b2v, acc2[mt][2]);
          acc2[mt][3] = MFMAH(aw, b3v, acc2[mt][3]);
        }
      }
      __syncthreads();
    }

    // ---- residual: h += acc2 + b2, packed 8B read/modify/write ----
    #pragma unroll
    for (int mt = 0; mt < 4; ++mt) {
      const int feat0 = (wave * 4 + mt) * 16 + quad * 4;
      float4 bb = *(const float4*)&b2l[feat0];
      #pragma unroll
      for (int nt = 0; nt < 4; ++nt) {
        const int row = nt * 16 + col;
        half4v oh = *(half4v*)&hA[row][feat0];
        half4v nh;
        #pragma unroll
        for (int p = 0; p < 4; ++p)
          nh[p] = (_Float16)((float)oh[p] + acc2[mt][nt][p] + ((const float*)&bb)[p]);
        *(half4v*)&hA[row][feat0] = nh;
      }
    }
    __syncthreads();
  }

  // ---- GEMM3': cw' = Wout^T @ h^T (+bout+cb+xhat), then distance ----
  floatx4 acc3[4][4];
  #pragma unroll
  for (int mt = 0; mt < 4; ++mt)
    #pragma unroll
    for (int nt = 0; nt < 4; ++nt) acc3[mt][nt] = zero4;

  const _Float16* wo_b = woutf + (wave * 4) * 512 + lane8;
  #pragma unroll 2
  for (int ks = 0; ks < 8; ++ks) {
    half8 b0 = *(const half8*)&hA[col][ks * 32 + quad * 8];
    half8 b1v = *(const half8*)&hA[16 + col][ks * 32 + quad * 8];
    half8 b2v = *(const half8*)&hA[32 + col][ks * 32 + quad * 8];
    half8 b3v = *(const half8*)&hA[48 + col][ks * 32 + quad * 8];
    const int ko = ks * 16 * 512;
    #pragma unroll
    for (int mt = 0; mt < 4; ++mt) {
      half8 aw = *(const half8*)(wo_b + ko + mt * 512);
      acc3[mt][0] = MFMAH(aw, b0, acc3[mt][0]);
      acc3[mt][1] = MFMAH(aw, b1v, acc3[mt][1]);
      acc3[mt][2] = MFMAH(aw, b2v, acc3[mt][2]);
      acc3[mt][3] = MFMAH(aw, b3v, acc3[mt][3]);
    }
  }

  float s[4] = {0.f, 0.f, 0.f, 0.f};
  #pragma unroll
  for (int mt = 0; mt < 4; ++mt) {
    const int d0 = (wave * 4 + mt) * 16 + quad * 4;
    float4 bo = *(const float4*)&bout[d0];
    float4 xv = *(const float4*)&x_s[d0];
    float4 xh4 = *(const float4*)&xh_s[d0];
    #pragma unroll
    for (int nt = 0; nt < 4; ++nt) {
      float4 cbv = *(const float4*)&cb[(k0 + nt * 16 + col) * D_ + d0];
      #pragma unroll
      for (int p = 0; p < 4; ++p) {
        float base = ((const float*)&bo)[p] + ((const float*)&xh4)[p];
        float xx = ((const float*)&xv)[p];
        float cw = acc3[mt][nt][p] + base + ((const float*)&cbv)[p];
        s[nt] += cw * (cw - 2.f * xx);   // -||x||^2 const: argmin-invariant
      }
    }
  }
  #pragma unroll
  for (int nt = 0; nt < 4; ++nt) {
    s[nt] += __shfl_xor(s[nt], 16, 64);
    s[nt] += __shfl_xor(s[nt], 32, 64);
  }
  if (quad == 0) {
    #pragma unroll
    for (int nt = 0; nt < 4; ++nt)
      dist_s[wave][nt * 16 + col] = s[nt];
  }
  __syncthreads();
  if (t < 64) {
    float d = dist_s[0][t] + dist_s[1][t] + dist_s[2][t] + dist_s[3][t];
    dists[b * (F_ * K_) + f * K_ + k0 + t] = d;
  }
}

// ---------------------------------------------------------------------------
// R12: fused top-8 + rescore. 512 blocks; the 4 blocks per b each compute the
// identical top-8 (register-held candidates, wave shuffle reduce, 1 barrier
// per pass — replaces the 70-barrier 0.5-occupancy k_top8), then rescore 2
// candidates (fmaf chains op-identical to R11/R2). Block q==0 writes topi.
__global__ __launch_bounds__(256) void k_resel(
    const float* __restrict__ u, const float* __restrict__ v,
    const float* __restrict__ W1, const float* __restrict__ b1,
    const float* __restrict__ W2, const float* __restrict__ b2,
    const float* __restrict__ Wout, const float* __restrict__ bout,
    const float* __restrict__ cb, const float* __restrict__ xhat,
    const float* __restrict__ x, const float* __restrict__ dists,
    int* __restrict__ topi, float* __restrict__ resc, float* __restrict__ cwr) {
  __shared__ float pv[8][4];
  __shared__ int   pi[8][4];
  __shared__ int   topc[8];
  __shared__ float hsA[H_], hsB[H_];
  __shared__ float hmA2[HFF_], hmB2[HFF_];
  __shared__ float redA[256], redB[256];

  const int blk = blockIdx.x, t = threadIdx.x;
  const int b = blk >> 2, q = blk & 3;
  const int wave = t >> 6, lane = t & 63;

  // ---- phase 1: top-8 of 2048 (first-occurrence tie semantics) ----
  float sv[8]; int si[8];
  #pragma unroll
  for (int i = 0; i < 8; ++i) {
    si[i] = t + 256 * i;
    sv[i] = dists[b * (F_ * K_) + si[i]];
  }
  for (int pass = 0; pass < 8; ++pass) {
    float v0 = sv[0]; int i0 = si[0];
    #pragma unroll
    for (int i = 1; i < 8; ++i)
      if (sv[i] < v0 || (sv[i] == v0 && si[i] < i0)) { v0 = sv[i]; i0 = si[i]; }
    #pragma unroll
    for (int m = 1; m < 64; m <<= 1) {
      const float ov = __shfl_xor(v0, m, 64);
      const int oi = __shfl_xor(i0, m, 64);
      if (ov < v0 || (ov == v0 && oi < i0)) { v0 = ov; i0 = oi; }
    }
    if (lane == 0) { pv[pass][wave] = v0; pi[pass][wave] = i0; }
    __syncthreads();
    float bv2 = pv[pass][0]; int bi2 = pi[pass][0];
    #pragma unroll
    for (int w = 1; w < 4; ++w) {
      const float ov = pv[pass][w]; const int oi = pi[pass][w];
      if (ov < bv2 || (ov == bv2 && oi < bi2)) { bv2 = ov; bi2 = oi; }
    }
    if (t == 0) topc[pass] = bi2;
    #pragma unroll
    for (int i = 0; i < 8; ++i)
      if (si[i] == bi2) sv[i] = 3.4e38f;
  }
  __syncthreads();
  if (q == 0 && t < 8) topi[b * 8 + t] = topc[t];

  // ---- phase 2: exact fp32 rescore of candidates q*2, q*2+1 ----
  const int bcA = b * 8 + q * 2, bcB = bcA + 1;
  const int idxA = topc[q * 2], idxB = topc[q * 2 + 1];
  const int kA = idxA & 255, kB = idxB & 255;
  const int bfA = b * F_ + (idxA >> 8), bfB = b * F_ + (idxB >> 8);

  hsA[t] = u[kA * H_ + t] + v[bfA * H_ + t];
  hsB[t] = u[kB * H_ + t] + v[bfB * H_ + t];
  __syncthreads();
  for (int l = 0; l < 2; ++l) {
    const float* W1l = W1 + l * (H_ * HFF_);
    const float* W2l = W2 + l * (HFF_ * H_);
    const float bb0 = b1[l * HFF_ + t], bb1 = b1[l * HFF_ + 256 + t];
    float a0A = bb0, a1A = bb1, a0B = bb0, a1B = bb1;
    #pragma unroll 4
    for (int i = 0; i < H_; ++i) {
      const float w0 = W1l[i * HFF_ + t];
      const float w1 = W1l[i * HFF_ + 256 + t];
      const float hA = hsA[i], hB = hsB[i];
      a0A = fmaf(hA, w0, a0A);
      a1A = fmaf(hA, w1, a1A);
      a0B = fmaf(hB, w0, a0B);
      a1B = fmaf(hB, w1, a1B);
    }
    hmA2[t] = fmaxf(a0A, 0.f);  hmA2[t + 256] = fmaxf(a1A, 0.f);
    hmB2[t] = fmaxf(a0B, 0.f);  hmB2[t + 256] = fmaxf(a1B, 0.f);
    __syncthreads();
    const float bb2 = b2[l * H_ + t];
    float hnA = hsA[t] + bb2, hnB = hsB[t] + bb2;
    #pragma unroll 4
    for (int jj = 0; jj < HFF_; ++jj) {
      const float w = W2l[jj * H_ + t];
      hnA = fmaf(hmA2[jj], w, hnA);
      hnB = fmaf(hmB2[jj], w, hnB);
    }
    __syncthreads();
    hsA[t] = hnA; hsB[t] = hnB;
    __syncthreads();
  }
  float cwA = bout[t] + cb[kA * D_ + t] + xhat[bfA * D_ + t];
  float cwB = bout[t] + cb[kB * D_ + t] + xhat[bfB * D_ + t];
  #pragma unroll 4
  for (int i = 0; i < H_; ++i) {
    const float w = Wout[i * D_ + t];
    cwA = fmaf(hsA[i], w, cwA);
    cwB = fmaf(hsB[i], w, cwB);
  }
  cwr[bcA * D_ + t] = cwA;
  cwr[bcB * D_ + t] = cwB;
  const float xx = x[b * D_ + t];
  redA[t] = cwA * (cwA - 2.f * xx);
  redB[t] = cwB * (cwB - 2.f * xx);
  __syncthreads();
  for (int s = 128; s > 0; s >>= 1) {
    if (t < s) { redA[t] += redA[t + s]; redB[t] += redB[t + s]; }
    __syncthreads();
  }
  if (t == 0) { resc[bcA] = redA[0]; resc[bcB] = redB[0]; }
}

// ---------------------------------------------------------------------------
// Trivial final — argmin over the 8 rescored candidates, copy cw row.
__global__ void k_final(const int* __restrict__ codes, const int* __restrict__ topi,
                        const float* __restrict__ resc, const float* __restrict__ cwr,
                        float* __restrict__ out) {
  __shared__ int win_sh;
  const int b = blockIdx.x, t = threadIdx.x;
  if (t == 0) {
    float bd = 3.4e38f; int bwin = 0; int bidx = 1 << 30;
    for (int c = 0; c < 8; ++c) {
      const float d = resc[b * 8 + c];
      const int ix = topi[b * 8 + c];
      if (d < bd || (d == bd && ix < bidx)) { bd = d; bwin = c; bidx = ix; }
    }
    win_sh = bwin;
  }
  __syncthreads();
  const int win = win_sh;
  out[b * D_ + t] = cwr[(b * 8 + win) * D_ + t];
  if (t < 2)
    out[B_ * D_ + t * B_ + b] = (float)codes[t * B_ + b];
  else if (t == 2)
    out[B_ * D_ + 2 * B_ + b] = (float)topi[b * 8 + win];
}

// ---------------------------------------------------------------------------
extern "C" void kernel_launch(void* const* d_in, const int* in_sizes, int n_in,
                              void* d_out, int out_size, void* d_ws, size_t ws_size,
                              hipStream_t stream) {
  const float* x    = (const float*)d_in[0];
  const float* xhat = (const float*)d_in[1];
  const int*   codes= (const int*)d_in[2];
  const float* cb   = (const float*)d_in[3];
  const float* Win  = (const float*)d_in[4];
  const float* bin  = (const float*)d_in[5];
  const float* Wcat = (const float*)d_in[6];
  const float* bcat = (const float*)d_in[7];
  const float* W1   = (const float*)d_in[8];
  const float* b1   = (const float*)d_in[9];
  const float* W2   = (const float*)d_in[10];
  const float* b2   = (const float*)d_in[11];
  const float* Wout = (const float*)d_in[12];
  const float* bout = (const float*)d_in[13];
  float* out = (float*)d_out;

  float* u     = (float*)d_ws;                  // 65536 f
  float* v     = u + K_ * H_;                   // 262144 f
  float* dists = v + B_ * F_ * H_;              // 262144 f
  float* resc  = dists + B_ * F_ * K_;          // 1024 f
  int*   topi  = (int*)(resc + 1024);           // 1024 i
  float* cwr   = (float*)(topi + 1024);         // 262144 f (8 cand x 256 per b)
  float* pad   = cwr + B_ * 8 * D_;             // 128 f pad (16B align)
  _Float16* w1f  = (_Float16*)(pad + 128);      // 2*H*HFF halves
  _Float16* w2f  = w1f + 2 * H_ * HFF_;
  _Float16* wof  = w2f + 2 * HFF_ * H_;

  k_prep<<<K_ + B_ * F_ + 2304, 256, 0, stream>>>(cb, Win, bin, Wcat, bcat, xhat,
                                                  W1, W2, Wout, u, v, w1f, w2f, wof);

  k_main<<<B_ * F_ * (K_ / RT), 256, 0, stream>>>(u, v, w1f, b1, w2f, b2,
                                                  wof, bout, cb, xhat, x, dists);

  k_resel<<<B_ * 4, 256, 0, stream>>>(u, v, W1, b1, W2, b2, Wout, bout, cb, xhat,
                                      x, dists, topi, resc, cwr);
  k_final<<<B_, 256, 0, stream>>>(codes, topi, resc, cwr, out);
}